// Round 23
// baseline (2224.244 us; speedup 1.0000x reference)
//
#include <hip/hip_runtime.h>
#include <hip/hip_bf16.h>

#define NN 100000   // nodes
#define NE 200000   // bonds
#define NB 600000   // bond neighbours
#define FN 133
#define FB 14
#define FIB 147     // FN+FB
#define DD 256
#define NEPAD (196 * 1024)
#define NNPAD (98 * 1024)

typedef __hip_bfloat16 bf16;
typedef __attribute__((ext_vector_type(8))) short short8;   // 8 bf16 = 4 VGPR
typedef __attribute__((ext_vector_type(4))) float f32x4;

__device__ __forceinline__ float hswish(float x) {
    float c = fminf(fmaxf(x + 3.f, 0.f), 6.f);
    return x * c * (1.f / 6.f);
}
__device__ __forceinline__ float sigmoidf(float x) {
    return 1.f / (1.f + __expf(-x));
}
__device__ __forceinline__ float tanh_fast(float x) {
    return 1.f - 2.f / (1.f + __expf(2.f * x));
}
__device__ __forceinline__ float bf2f(unsigned short u) {
    union { unsigned int i; float f; } c; c.i = (unsigned int)u << 16; return c.f;
}
__device__ __forceinline__ unsigned short f2bf(float v) {
    bf16 b = __float2bfloat16(v);
    unsigned short u; __builtin_memcpy(&u, &b, 2); return u;
}
__device__ __forceinline__ void unp8(short8 v, float* f) {
    #pragma unroll
    for (int j = 0; j < 8; j++) {
        short s = v[j]; unsigned short u; __builtin_memcpy(&u, &s, 2);
        f[j] = bf2f(u);
    }
}
__device__ __forceinline__ uint4 pk8(const float* f) {
    uint4 v;
    v.x = f2bf(f[0]) | ((unsigned)f2bf(f[1]) << 16);
    v.y = f2bf(f[2]) | ((unsigned)f2bf(f[3]) << 16);
    v.z = f2bf(f[4]) | ((unsigned)f2bf(f[5]) << 16);
    v.w = f2bf(f[6]) | ((unsigned)f2bf(f[7]) << 16);
    return v;
}

// ---------------- fill (ws-guard sentinel only) -------------------------
__global__ __launch_bounds__(256) void fill_kernel(float* __restrict__ p, float v, long n4) {
    long i = (long)blockIdx.x * 256 + threadIdx.x;
    long st = (long)gridDim.x * 256;
    float4 z = {v, v, v, v};
    for (; i < n4; i += st) ((float4*)p)[i] = z;
}

// ---------------- IB row build (shared body) ----------------------------
__device__ __forceinline__ void ib_row(
    const float* __restrict__ node, const float* __restrict__ bond,
    const int* __restrict__ i_idx, bf16* __restrict__ IB, int row, int lane)
{
    if (lane >= 40) return;
    int src = i_idx[row];
    int c = lane * 4;
    unsigned short us[4];
    #pragma unroll
    for (int j = 0; j < 4; j++) {
        int k = c + j;
        float v = 0.f;
        if (k < FN)       v = node[(size_t)src * FN + k];
        else if (k < FIB) v = bond[(size_t)row * FB + (k - FN)];
        us[j] = f2bf(v);
    }
    ushort4 o = {us[0], us[1], us[2], us[3]};
    *(ushort4*)((unsigned short*)IB + (size_t)row * 160 + c) = o;
}

// ---------------- weight pack body (fixed layout, 786432 elems) ---------
__device__ __forceinline__ void pack_body(
    int idx,
    const float* __restrict__ w_r, const float* __restrict__ w_z,
    const float* __restrict__ w_bond, const float* __restrict__ w_m,
    const float* __restrict__ w_node, const float* __restrict__ w_n,
    const float* __restrict__ u_, const float* __restrict__ u_n,
    const float* __restrict__ w_bf, const float* __restrict__ w_nf,
    bf16* __restrict__ wt)
{
    if (idx >= 786432) return;
    float v = 0.f;
    if (idx < 245760) {
        int r = idx / 40960;
        int loc = idx - r * 40960;
        int n = loc / 160, k = loc % 160;
        const float* W = (r == 0) ? w_r : (r == 1) ? w_z : (r == 2) ? w_bond
                       : (r == 3) ? w_m : (r == 4) ? w_node : w_n;
        int K1 = (r < 4) ? FIB : FN;
        if (k < K1) v = W[(size_t)k * DD + n];
    } else if (idx < 442368) {
        int r = (idx - 245760) / 65536;
        int loc = (idx - 245760) - r * 65536;
        int n = loc / 256, k = loc % 256;
        const float* W = (r == 0) ? (w_r + (size_t)FIB * DD)
                       : (r == 1) ? (w_z + (size_t)FIB * DD) : u_;
        v = W[(size_t)k * DD + n];
    } else if (idx < 573440) {
        int loc = idx - 442368;
        int n = loc / 512, k = loc % 512;
        v = u_n[(size_t)k * DD + n];
    } else {
        int r = (idx - 573440) / 106496;
        int loc = (idx - 573440) - r * 106496;
        int n = loc / 416, k = loc % 416;
        const float* W = r ? w_nf : w_bf;
        int K1 = r ? FN : FIB;
        if (k < K1)        v = W[(size_t)k * DD + n];
        else if (k >= 160) v = W[(size_t)(K1 + k - 160) * DD + n];
    }
    wt[idx] = __float2bfloat16(v);
}

// ---- zero_pack: [zero CSR counts (1176 blk)] ∥ [pack weights (3072 blk)]
__global__ __launch_bounds__(256) void zero_pack(
    int* __restrict__ offE, int* __restrict__ offN,
    const float* __restrict__ w_r, const float* __restrict__ w_z,
    const float* __restrict__ w_bond, const float* __restrict__ w_m,
    const float* __restrict__ w_node, const float* __restrict__ w_n,
    const float* __restrict__ u_, const float* __restrict__ u_n,
    const float* __restrict__ w_bf, const float* __restrict__ w_nf,
    bf16* __restrict__ wt)
{
    int b = blockIdx.x;
    if (b < 1176) {
        int i = b * 256 + threadIdx.x;
        if (i < NEPAD) offE[i] = 0;
        else if (i < NEPAD + NNPAD) offN[i - NEPAD] = 0;
    } else {
        pack_body((b - 1176) * 256 + threadIdx.x,
                  w_r, w_z, w_bond, w_m, w_node, w_n, u_, u_n, w_bf, w_nf, wt);
    }
}

__global__ __launch_bounds__(256) void count2_kernel(
    const int* __restrict__ ij, const int* __restrict__ jidx,
    int* __restrict__ offE, int* __restrict__ offN)
{
    int i = blockIdx.x * 256 + threadIdx.x;
    if (i < NB) atomicAdd(&offE[ij[i]], 1);
    else if (i < NB + NE) atomicAdd(&offN[jidx[i - NB]], 1);
}

__global__ __launch_bounds__(256) void scan_block2(
    int* __restrict__ offE, int* __restrict__ offN,
    int* __restrict__ bsumE, int* __restrict__ bsumN)
{
    __shared__ int lds[256];
    int* data; int* bs; int bb;
    if ((int)blockIdx.x < 196) { data = offE; bs = bsumE; bb = blockIdx.x; }
    else                       { data = offN; bs = bsumN; bb = blockIdx.x - 196; }
    int base = bb * 1024 + threadIdx.x * 4;
    int c0 = data[base], c1 = data[base + 1], c2 = data[base + 2], c3 = data[base + 3];
    int t = c0 + c1 + c2 + c3;
    lds[threadIdx.x] = t;
    __syncthreads();
    int x = t;
    for (int off = 1; off < 256; off <<= 1) {
        int y = (threadIdx.x >= off) ? lds[threadIdx.x - off] : 0;
        __syncthreads();
        x += y; lds[threadIdx.x] = x;
        __syncthreads();
    }
    int excl = x - t;
    data[base] = excl; data[base + 1] = excl + c0;
    data[base + 2] = excl + c0 + c1; data[base + 3] = excl + c0 + c1 + c2;
    if (threadIdx.x == 255) bs[bb] = x;
}

__global__ __launch_bounds__(256) void scan_bsum2(int* __restrict__ bsumE, int* __restrict__ bsumN)
{
    __shared__ int lds[256];
    int* bs = blockIdx.x ? bsumN : bsumE;
    int n = blockIdx.x ? 98 : 196;
    int t = (threadIdx.x < n) ? bs[threadIdx.x] : 0;
    lds[threadIdx.x] = t;
    __syncthreads();
    int x = t;
    for (int off = 1; off < 256; off <<= 1) {
        int y = (threadIdx.x >= off) ? lds[threadIdx.x - off] : 0;
        __syncthreads();
        x += y; lds[threadIdx.x] = x;
        __syncthreads();
    }
    if (threadIdx.x < n) bs[threadIdx.x] = x - t;
}

// merged scan_add + copy (offX finalized and mirrored into curX)
__global__ __launch_bounds__(256) void scan_add_copy2(
    int* __restrict__ offE, int* __restrict__ offN,
    const int* __restrict__ bsumE, const int* __restrict__ bsumN,
    int* __restrict__ curE, int* __restrict__ curN)
{
    int i = blockIdx.x * 256 + threadIdx.x;
    if (i < NEPAD) {
        int v = offE[i] + bsumE[i >> 10];
        offE[i] = v; curE[i] = v;
    } else if (i < NEPAD + NNPAD) {
        int j = i - NEPAD;
        int v = offN[j] + bsumN[j >> 10];
        offN[j] = v; curN[j] = v;
    }
}

// ---- lists_ib: [CSR list fill (3125 blk)] ∥ [IB build (50000 blk)] -----
__global__ __launch_bounds__(256) void lists_ib(
    const int* __restrict__ ij, const int* __restrict__ ki, const int* __restrict__ jidx,
    int* __restrict__ curE, int* __restrict__ curN,
    int* __restrict__ nbLst, int* __restrict__ agLst,
    const float* __restrict__ node, const float* __restrict__ bond,
    const int* __restrict__ i_idx, bf16* __restrict__ IB)
{
    int b = blockIdx.x;
    if (b < 3125) {
        int i = b * 256 + threadIdx.x;
        if (i < NB) { int p = atomicAdd(&curE[ij[i]], 1); nbLst[p] = ki[i]; }
        else if (i < NB + NE) {
            int e = i - NB;
            int p = atomicAdd(&curN[jidx[e]], 1); agLst[p] = e;
        }
    } else {
        int row = (b - 3125) * 4 + (threadIdx.x >> 6);
        if (row < NE) ib_row(node, bond, i_idx, IB, row, threadIdx.x & 63);
    }
}

// -------- fused seg_s + seg_r: 2-way-unrolled CSR walk (ILP) ------------
__global__ __launch_bounds__(256) void seg_sr_kernel(
    const bf16* __restrict__ MB, const bf16* __restrict__ TR,
    const bf16* __restrict__ PR, const int* __restrict__ off,
    const int* __restrict__ lst,
    bf16* __restrict__ S, bf16* __restrict__ R)
{
    int sid = blockIdx.x * 4 + (threadIdx.x >> 6);
    if (sid >= NE) return;
    int lane = threadIdx.x & 63;
    ushort4 up = *(const ushort4*)((const unsigned short*)PR + (size_t)sid * DD + lane * 4);
    float p0 = bf2f(up.x), p1 = bf2f(up.y), p2 = bf2f(up.z), p3 = bf2f(up.w);
    int b = off[sid], e = off[sid + 1];
    float s0 = 0, s1 = 0, s2 = 0, s3 = 0;
    float r0 = 0, r1 = 0, r2 = 0, r3 = 0;
    int t = b;
    for (; t + 1 < e; t += 2) {
        int src0 = lst[t];
        int src1 = lst[t + 1];
        const unsigned short* m0p = (const unsigned short*)MB + (size_t)src0 * DD + lane * 4;
        const unsigned short* t0p = (const unsigned short*)TR + (size_t)src0 * DD + lane * 4;
        const unsigned short* m1p = (const unsigned short*)MB + (size_t)src1 * DD + lane * 4;
        const unsigned short* t1p = (const unsigned short*)TR + (size_t)src1 * DD + lane * 4;
        ushort4 um0 = *(const ushort4*)m0p;
        ushort4 ut0 = *(const ushort4*)t0p;
        ushort4 um1 = *(const ushort4*)m1p;
        ushort4 ut1 = *(const ushort4*)t1p;
        float a0 = bf2f(um0.x), a1 = bf2f(um0.y), a2 = bf2f(um0.z), a3 = bf2f(um0.w);
        float c0 = bf2f(um1.x), c1 = bf2f(um1.y), c2 = bf2f(um1.z), c3 = bf2f(um1.w);
        s0 += a0 + c0; s1 += a1 + c1; s2 += a2 + c2; s3 += a3 + c3;
        r0 += sigmoidf(p0 + bf2f(ut0.x)) * a0 + sigmoidf(p0 + bf2f(ut1.x)) * c0;
        r1 += sigmoidf(p1 + bf2f(ut0.y)) * a1 + sigmoidf(p1 + bf2f(ut1.y)) * c1;
        r2 += sigmoidf(p2 + bf2f(ut0.z)) * a2 + sigmoidf(p2 + bf2f(ut1.z)) * c2;
        r3 += sigmoidf(p3 + bf2f(ut0.w)) * a3 + sigmoidf(p3 + bf2f(ut1.w)) * c3;
    }
    if (t < e) {
        int src = lst[t];
        ushort4 um = *(const ushort4*)((const unsigned short*)MB + (size_t)src * DD + lane * 4);
        ushort4 ut = *(const ushort4*)((const unsigned short*)TR + (size_t)src * DD + lane * 4);
        float m0 = bf2f(um.x), m1 = bf2f(um.y), m2 = bf2f(um.z), m3 = bf2f(um.w);
        s0 += m0; s1 += m1; s2 += m2; s3 += m3;
        r0 += sigmoidf(p0 + bf2f(ut.x)) * m0;
        r1 += sigmoidf(p1 + bf2f(ut.y)) * m1;
        r2 += sigmoidf(p2 + bf2f(ut.z)) * m2;
        r3 += sigmoidf(p3 + bf2f(ut.w)) * m3;
    }
    ushort4 os = {f2bf(s0), f2bf(s1), f2bf(s2), f2bf(s3)};
    ushort4 orr = {f2bf(r0), f2bf(r1), f2bf(r2), f2bf(r3)};
    *(ushort4*)((unsigned short*)S + (size_t)sid * DD + lane * 4) = os;
    *(ushort4*)((unsigned short*)R + (size_t)sid * DD + lane * 4) = orr;
}

// ======== blend2: BM=64 x BN=128, two sequential K=256 phases ===========
// LDS 27.6 KB -> 5 blocks/CU (wave-capped). Grid (3125, 2).
__global__ __launch_bounds__(512) void blend2(
    const bf16* __restrict__ S, const bf16* __restrict__ R,
    const bf16* __restrict__ WTz2, const bf16* __restrict__ WTu,
    const bf16* __restrict__ PZ, const bf16* __restrict__ PM,
    bf16* __restrict__ MB)
{
    __shared__ __align__(16) unsigned short As[64 * 72];    // 9.2 KB
    __shared__ __align__(16) unsigned short Bs[128 * 72];   // 18.4 KB
    const int tid = threadIdx.x;
    const int row0 = blockIdx.x * 64, col0 = blockIdx.y * 128;
    const int lane = tid & 63, w = tid >> 6;
    const int wr = w >> 1, wc = w & 1;      // 4 x 2 wave grid, MSPAN=16
    const int fr = lane & 15, ko = (lane >> 4) * 8;

    f32x4 acc1[4] = {};
    f32x4 acc2[4] = {};

    #pragma unroll
    for (int ph = 0; ph < 2; ph++) {
        const bf16* A = (ph == 0) ? S : R;
        const bf16* W = (ph == 0) ? WTz2 : WTu;
        for (int k0 = 0; k0 < DD; k0 += 64) {
            if (tid < 256) {
                int mloc = tid >> 2, kq = (tid & 3) * 16;
                int mg = row0 + mloc;
                uint4 va  = *(const uint4*)((const unsigned short*)A + (size_t)mg * DD + k0 + kq);
                uint4 va2 = *(const uint4*)((const unsigned short*)A + (size_t)mg * DD + k0 + kq + 8);
                *(uint4*)&As[mloc * 72 + kq] = va;
                *(uint4*)&As[mloc * 72 + kq + 8] = va2;
            }
            {
                int nloc = tid >> 2, kq = (tid & 3) * 16;
                uint4 vb  = *(const uint4*)((const unsigned short*)W + (size_t)(col0 + nloc) * DD + k0 + kq);
                uint4 vb2 = *(const uint4*)((const unsigned short*)W + (size_t)(col0 + nloc) * DD + k0 + kq + 8);
                *(uint4*)&Bs[nloc * 72 + kq] = vb;
                *(uint4*)&Bs[nloc * 72 + kq + 8] = vb2;
            }
            __syncthreads();
            #pragma unroll
            for (int kk = 0; kk < 64; kk += 32) {
                short8 af = *(const short8*)&As[(wr * 16 + fr) * 72 + kk + ko];
                short8 bf8[4];
                #pragma unroll
                for (int nf = 0; nf < 4; nf++)
                    bf8[nf] = *(const short8*)&Bs[(wc * 64 + nf * 16 + fr) * 72 + kk + ko];
                #pragma unroll
                for (int nf = 0; nf < 4; nf++) {
                    if (ph == 0)
                        acc1[nf] = __builtin_amdgcn_mfma_f32_16x16x32_bf16(af, bf8[nf], acc1[nf], 0, 0, 0);
                    else
                        acc2[nf] = __builtin_amdgcn_mfma_f32_16x16x32_bf16(af, bf8[nf], acc2[nf], 0, 0, 0);
                }
            }
            __syncthreads();
        }
    }

    #pragma unroll
    for (int i = 0; i < 4; i++) {
        int mloc = wr * 16 + (lane >> 4) * 4 + i;
        int gm = row0 + mloc;
        if (gm >= NE) continue;
        #pragma unroll
        for (int nf = 0; nf < 4; nf++) {
            int gc = col0 + wc * 64 + nf * 16 + fr;
            size_t idx = (size_t)gm * DD + gc;
            float z  = sigmoidf(acc1[nf][i] + __bfloat162float(PZ[idx]));
            float mm = tanh_fast(acc2[nf][i] + __bfloat162float(PM[idx]));
            float s  = __bfloat162float(S[idx]);
            MB[idx] = __float2bfloat16((1.f - z) * s + z * mm);
        }
    }
}

// ======== pairk: [TR-GEMM BN=256] ∥ [node-update w/ AGG] ∥ [IB build] ===
__global__ __launch_bounds__(512) void pairk(
    int trblocks,
    const bf16* __restrict__ MBn, const bf16* __restrict__ WTr2,
    bf16* __restrict__ TRo,
    const bf16* __restrict__ MN, const int* __restrict__ offN,
    const int* __restrict__ agLst, const bf16* __restrict__ WTnu,
    const bf16* __restrict__ PN, bf16* __restrict__ MNout,
    const float* __restrict__ node, const float* __restrict__ bond,
    const int* __restrict__ i_idx, bf16* __restrict__ IBout)
{
    __shared__ __align__(16) unsigned short As[128 * 40];   // 10 KB
    __shared__ __align__(16) unsigned short Bs[256 * 40];   // 20 KB
    const int tid = threadIdx.x, lane = tid & 63, w = tid >> 6;
    const int fr = lane & 15, ko = (lane >> 4) * 8;
    const int mloc = tid >> 2, kq = (tid & 3) * 8;

    if ((int)blockIdx.x < trblocks) {
        const int row0 = blockIdx.x * 128;
        const int wr = w >> 2, wc = w & 3;
        const int mg = row0 + mloc;
        f32x4 acc[4][4] = {};
        for (int k0 = 0; k0 < 256; k0 += 32) {
            uint4 v = {0, 0, 0, 0};
            if (mg < NE)
                v = *(const uint4*)((const unsigned short*)MBn + (size_t)mg * DD + k0 + kq);
            *(uint4*)&As[mloc * 40 + kq] = v;
            #pragma unroll
            for (int it = 0; it < 2; ++it) {
                int nloc = (tid >> 2) + it * 128;
                *(uint4*)&Bs[nloc * 40 + kq] =
                    *(const uint4*)((const unsigned short*)WTr2 + (size_t)nloc * DD + k0 + kq);
            }
            __syncthreads();
            short8 af[4], bw[4];
            #pragma unroll
            for (int mf = 0; mf < 4; mf++)
                af[mf] = *(const short8*)&As[(wr * 64 + mf * 16 + fr) * 40 + ko];
            #pragma unroll
            for (int nf = 0; nf < 4; nf++)
                bw[nf] = *(const short8*)&Bs[(wc * 64 + nf * 16 + fr) * 40 + ko];
            #pragma unroll
            for (int mf = 0; mf < 4; mf++)
                #pragma unroll
                for (int nf = 0; nf < 4; nf++)
                    acc[mf][nf] = __builtin_amdgcn_mfma_f32_16x16x32_bf16(af[mf], bw[nf], acc[mf][nf], 0, 0, 0);
            __syncthreads();
        }
        #pragma unroll
        for (int mf = 0; mf < 4; mf++)
            #pragma unroll
            for (int i = 0; i < 4; i++) {
                int ml = wr * 64 + mf * 16 + (lane >> 4) * 4 + i;
                int gm = row0 + ml;
                if (gm >= NE) continue;
                #pragma unroll
                for (int nf = 0; nf < 4; nf++) {
                    int gc = wc * 64 + nf * 16 + fr;
                    TRo[(size_t)gm * DD + gc] = __float2bfloat16(acc[mf][nf][i]);
                }
            }
    } else if ((int)blockIdx.x < trblocks + 782) {
        const int bx = blockIdx.x - trblocks;
        const int row0 = bx * 128;
        const int wr = w >> 2, wc = w & 3;
        const int mg = row0 + mloc;
        int eb = 0, ee = 0;
        if (mg < NN) { eb = offN[mg]; ee = offN[mg + 1]; }
        f32x4 acc[4][4] = {};
        for (int k0 = 0; k0 < 512; k0 += 32) {
            const int kg = k0 + kq;
            uint4 v = {0, 0, 0, 0};
            if (mg < NN) {
                if (kg < 256) {
                    v = *(const uint4*)((const unsigned short*)MN + (size_t)mg * DD + kg);
                } else {
                    const int kk = kg - 256;
                    float a[8] = {0, 0, 0, 0, 0, 0, 0, 0};
                    int t = eb;
                    for (; t + 1 < ee; t += 2) {
                        int s0i = agLst[t];
                        int s1i = agLst[t + 1];
                        short8 v0 = *(const short8*)((const unsigned short*)MBn + (size_t)s0i * DD + kk);
                        short8 v1 = *(const short8*)((const unsigned short*)MBn + (size_t)s1i * DD + kk);
                        float m0[8], m1[8];
                        unp8(v0, m0); unp8(v1, m1);
                        #pragma unroll
                        for (int j = 0; j < 8; j++) a[j] += m0[j] + m1[j];
                    }
                    if (t < ee) {
                        int src = agLst[t];
                        float m8[8];
                        unp8(*(const short8*)((const unsigned short*)MBn + (size_t)src * DD + kk), m8);
                        #pragma unroll
                        for (int j = 0; j < 8; j++) a[j] += m8[j];
                    }
                    v = pk8(a);
                }
            }
            *(uint4*)&As[mloc * 40 + kq] = v;
            #pragma unroll
            for (int it = 0; it < 2; ++it) {
                int nloc = (tid >> 2) + it * 128;
                *(uint4*)&Bs[nloc * 40 + kq] =
                    *(const uint4*)((const unsigned short*)WTnu + (size_t)nloc * 512 + k0 + kq);
            }
            __syncthreads();
            short8 af[4], bw[4];
            #pragma unroll
            for (int mf = 0; mf < 4; mf++)
                af[mf] = *(const short8*)&As[(wr * 64 + mf * 16 + fr) * 40 + ko];
            #pragma unroll
            for (int nf = 0; nf < 4; nf++)
                bw[nf] = *(const short8*)&Bs[(wc * 64 + nf * 16 + fr) * 40 + ko];
            #pragma unroll
            for (int mf = 0; mf < 4; mf++)
                #pragma unroll
                for (int nf = 0; nf < 4; nf++)
                    acc[mf][nf] = __builtin_amdgcn_mfma_f32_16x16x32_bf16(af[mf], bw[nf], acc[mf][nf], 0, 0, 0);
            __syncthreads();
        }
        #pragma unroll
        for (int mf = 0; mf < 4; mf++)
            #pragma unroll
            for (int i = 0; i < 4; i++) {
                int ml = wr * 64 + mf * 16 + (lane >> 4) * 4 + i;
                int gm = row0 + ml;
                if (gm >= NN) continue;
                #pragma unroll
                for (int nf = 0; nf < 4; nf++) {
                    int gc = wc * 64 + nf * 16 + fr;
                    size_t idx = (size_t)gm * DD + gc;
                    MNout[idx] = __float2bfloat16(
                        hswish(acc[mf][nf][i] + __bfloat162float(PN[idx])));
                }
            }
    } else {
        int b2 = blockIdx.x - trblocks - 782;
        int row = b2 * 8 + (tid >> 6);
        if (row < NE) ib_row(node, bond, i_idx, IBout, row, lane);
    }
}

// ======== pre_quad64: BM=64 — 4 GEMMs over one LDS-cached A (K=160) =====
// blocks 0..6249: bond quad (bx = b%3125, by = b/3125)
// blocks 6250..9375: node dual (bx = b2%1563, by = b2/1563)
__global__ __launch_bounds__(512) void pre_quad64(
    const bf16* __restrict__ IBbf,
    const bf16* __restrict__ WTr, const bf16* __restrict__ WTz1,
    const float* __restrict__ b_r, const float* __restrict__ b_z,
    bf16* __restrict__ PR, bf16* __restrict__ PZ,
    const bf16* __restrict__ WTb, const bf16* __restrict__ WTm1,
    const float* __restrict__ b_bond, const float* __restrict__ b_m,
    bf16* __restrict__ MB, bf16* __restrict__ PM,
    const float* __restrict__ node,
    const bf16* __restrict__ WTn0, const bf16* __restrict__ WTn,
    const float* __restrict__ b_node, const float* __restrict__ b_n,
    bf16* __restrict__ MN, bf16* __restrict__ PN)
{
    __shared__ __align__(16) unsigned short Af[64 * 168];   // 21 KB (stride-168 pad)
    __shared__ __align__(16) unsigned short B1[128 * 40];   // 10 KB
    __shared__ __align__(16) unsigned short B2[128 * 40];   // 10 KB
    const int tid = threadIdx.x;
    const int lane = tid & 63, w = tid >> 6;
    const int fr = lane & 15, ko = (lane >> 4) * 8;
    const int wr = w >> 1, wc = w & 1;      // 4x2 waves, MSPAN=16
    int b = blockIdx.x;

    if (b < 6250) {
        const int bx = b % 3125, by = b / 3125;
        const int row0 = bx * 64, col0 = by * 128;
        // ---- load full A tile (64 x 160 bf16) once ----
        #pragma unroll
        for (int it = 0; it < 3; ++it) {
            int idx = tid + it * 512;           // 0..1535 (need 1280)
            if (idx < 1280) {
                int mloc = idx / 20, kq = (idx % 20) * 8;
                int mg = row0 + mloc;
                uint4 v = *(const uint4*)((const unsigned short*)IBbf + (size_t)mg * 160 + kq);
                *(uint4*)&Af[mloc * 168 + kq] = v;
            }
        }
        __syncthreads();

        #pragma unroll
        for (int ph = 0; ph < 2; ph++) {
            const bf16* W1 = ph ? WTb : WTr;
            const bf16* W2 = ph ? WTm1 : WTz1;
            f32x4 a1[4] = {};
            f32x4 a2[4] = {};
            for (int k0 = 0; k0 < 160; k0 += 32) {
                {
                    int nloc = tid >> 2, kq = (tid & 3) * 8;
                    *(uint4*)&B1[nloc * 40 + kq] =
                        *(const uint4*)((const unsigned short*)W1 + (size_t)(col0 + nloc) * 160 + k0 + kq);
                    *(uint4*)&B2[nloc * 40 + kq] =
                        *(const uint4*)((const unsigned short*)W2 + (size_t)(col0 + nloc) * 160 + k0 + kq);
                }
                __syncthreads();
                short8 af = *(const short8*)&Af[(wr * 16 + fr) * 168 + k0 + ko];
                short8 b1f[4], b2f[4];
                #pragma unroll
                for (int nf = 0; nf < 4; nf++) {
                    b1f[nf] = *(const short8*)&B1[(wc * 64 + nf * 16 + fr) * 40 + ko];
                    b2f[nf] = *(const short8*)&B2[(wc * 64 + nf * 16 + fr) * 40 + ko];
                }
                #pragma unroll
                for (int nf = 0; nf < 4; nf++) {
                    a1[nf] = __builtin_amdgcn_mfma_f32_16x16x32_bf16(af, b1f[nf], a1[nf], 0, 0, 0);
                    a2[nf] = __builtin_amdgcn_mfma_f32_16x16x32_bf16(af, b2f[nf], a2[nf], 0, 0, 0);
                }
                __syncthreads();
            }
            // epilogue (no LDS use)
            #pragma unroll
            for (int i = 0; i < 4; i++) {
                int mloc = wr * 16 + (lane >> 4) * 4 + i;
                int gm = row0 + mloc;
                #pragma unroll
                for (int nf = 0; nf < 4; nf++) {
                    int gc = col0 + wc * 64 + nf * 16 + fr;
                    size_t idx = (size_t)gm * DD + gc;
                    if (ph == 0) {
                        PR[idx] = __float2bfloat16(a1[nf][i] + b_r[gc]);
                        PZ[idx] = __float2bfloat16(a2[nf][i] + b_z[gc]);
                    } else {
                        MB[idx] = __float2bfloat16(hswish(a1[nf][i] + b_bond[gc]));
                        PM[idx] = __float2bfloat16(a2[nf][i] + b_m[gc]);
                    }
                }
            }
        }
    } else {
        // ---- MN/PN dual: A = node (f32, K real 133, padded 160), BM=64 ----
        const int b2 = b - 6250;
        const int bx = b2 % 1563, by = b2 / 1563;
        const int row0 = bx * 64, col0 = by * 128;
        f32x4 a1[4] = {};
        f32x4 a2[4] = {};
        for (int k0 = 0; k0 < 160; k0 += 32) {
            if (tid < 256) {
                int mloc = tid >> 2, kq = (tid & 3) * 8;
                int mg = row0 + mloc;
                uint4 v = {0, 0, 0, 0};
                if (mg < NN) {
                    const float* fp = node + (size_t)mg * FN;
                    unsigned short us[8];
                    #pragma unroll
                    for (int j = 0; j < 8; j++) {
                        int kk = k0 + kq + j;
                        us[j] = (kk < FN) ? f2bf(fp[kk]) : (unsigned short)0;
                    }
                    v.x = us[0] | ((unsigned)us[1] << 16);
                    v.y = us[2] | ((unsigned)us[3] << 16);
                    v.z = us[4] | ((unsigned)us[5] << 16);
                    v.w = us[6] | ((unsigned)us[7] << 16);
                }
                *(uint4*)&Af[mloc * 40 + kq] = v;
            }
            {
                int nloc = tid >> 2, kq = (tid & 3) * 8;
                *(uint4*)&B1[nloc * 40 + kq] =
                    *(const uint4*)((const unsigned short*)WTn0 + (size_t)(col0 + nloc) * 160 + k0 + kq);
                *(uint4*)&B2[nloc * 40 + kq] =
                    *(const uint4*)((const unsigned short*)WTn + (size_t)(col0 + nloc) * 160 + k0 + kq);
            }
            __syncthreads();
            short8 af = *(const short8*)&Af[(wr * 16 + fr) * 40 + ko];
            short8 b1f[4], b2f[4];
            #pragma unroll
            for (int nf = 0; nf < 4; nf++) {
                b1f[nf] = *(const short8*)&B1[(wc * 64 + nf * 16 + fr) * 40 + ko];
                b2f[nf] = *(const short8*)&B2[(wc * 64 + nf * 16 + fr) * 40 + ko];
            }
            #pragma unroll
            for (int nf = 0; nf < 4; nf++) {
                a1[nf] = __builtin_amdgcn_mfma_f32_16x16x32_bf16(af, b1f[nf], a1[nf], 0, 0, 0);
                a2[nf] = __builtin_amdgcn_mfma_f32_16x16x32_bf16(af, b2f[nf], a2[nf], 0, 0, 0);
            }
            __syncthreads();
        }
        #pragma unroll
        for (int i = 0; i < 4; i++) {
            int mloc = wr * 16 + (lane >> 4) * 4 + i;
            int gm = row0 + mloc;
            if (gm >= NN) continue;
            #pragma unroll
            for (int nf = 0; nf < 4; nf++) {
                int gc = col0 + wc * 64 + nf * 16 + fr;
                size_t idx = (size_t)gm * DD + gc;
                MN[idx] = __float2bfloat16(hswish(a1[nf][i] + b_node[gc]));
                PN[idx] = __float2bfloat16(a2[nf][i] + b_n[gc]);
            }
        }
    }
}

// ---- tr0: TR_0 = MB @ WTr2 (BM=128, BN=256) ----------------------------
__global__ __launch_bounds__(512) void tr0_kernel(
    const bf16* __restrict__ MBn, const bf16* __restrict__ WTr2,
    bf16* __restrict__ TRo)
{
    __shared__ __align__(16) unsigned short As[128 * 40];
    __shared__ __align__(16) unsigned short Bs[256 * 40];
    const int tid = threadIdx.x, lane = tid & 63, w = tid >> 6;
    const int fr = lane & 15, ko = (lane >> 4) * 8;
    const int mloc = tid >> 2, kq = (tid & 3) * 8;
    const int row0 = blockIdx.x * 128;
    const int wr = w >> 2, wc = w & 3;
    const int mg = row0 + mloc;
    f32x4 acc[4][4] = {};
    for (int k0 = 0; k0 < 256; k0 += 32) {
        uint4 v = {0, 0, 0, 0};
        if (mg < NE)
            v = *(const uint4*)((const unsigned short*)MBn + (size_t)mg * DD + k0 + kq);
        *(uint4*)&As[mloc * 40 + kq] = v;
        #pragma unroll
        for (int it = 0; it < 2; ++it) {
            int nloc = (tid >> 2) + it * 128;
            *(uint4*)&Bs[nloc * 40 + kq] =
                *(const uint4*)((const unsigned short*)WTr2 + (size_t)nloc * DD + k0 + kq);
        }
        __syncthreads();
        short8 af[4], bw[4];
        #pragma unroll
        for (int mf = 0; mf < 4; mf++)
            af[mf] = *(const short8*)&As[(wr * 64 + mf * 16 + fr) * 40 + ko];
        #pragma unroll
        for (int nf = 0; nf < 4; nf++)
            bw[nf] = *(const short8*)&Bs[(wc * 64 + nf * 16 + fr) * 40 + ko];
        #pragma unroll
        for (int mf = 0; mf < 4; mf++)
            #pragma unroll
            for (int nf = 0; nf < 4; nf++)
                acc[mf][nf] = __builtin_amdgcn_mfma_f32_16x16x32_bf16(af[mf], bw[nf], acc[mf][nf], 0, 0, 0);
        __syncthreads();
    }
    #pragma unroll
    for (int mf = 0; mf < 4; mf++)
        #pragma unroll
        for (int i = 0; i < 4; i++) {
            int ml = wr * 64 + mf * 16 + (lane >> 4) * 4 + i;
            int gm = row0 + ml;
            if (gm >= NE) continue;
            #pragma unroll
            for (int nf = 0; nf < 4; nf++) {
                int gc = wc * 64 + nf * 16 + fr;
                TRo[(size_t)gm * DD + gc] = __float2bfloat16(acc[mf][nf][i]);
            }
        }
}

// ---------------- bg64_body: BM=64, BN=256, NT=512 (f32 out) ------------
__device__ __forceinline__ void bg64_body(
    const void* __restrict__ A1, int a1stride, int a1kw, int a1real, int a1f32,
    const void* __restrict__ A2, int a2stride, int a2kw, int a2real, int a2f32,
    const bf16* __restrict__ WT1, int KT, const float* __restrict__ bias1,
    float* __restrict__ out1, int M, int row0,
    unsigned short* As, unsigned short* Bs)
{
    const int tid = threadIdx.x;
    const int lane = tid & 63, w = tid >> 6;
    const int wr = w >> 2, wc = w & 3;
    const int fr = lane & 15, ko = (lane >> 4) * 8;

    f32x4 acc[2][4] = {};

    for (int k0 = 0; k0 < KT; k0 += 32) {
        if (tid < 256) {
            int mloc = tid >> 2, kq = (tid & 3) * 8;
            int mg = row0 + mloc;
            int kg = k0 + kq;
            const void* p; int stride, real, isf; int kk;
            if (kg < a1kw) { p = A1; stride = a1stride; real = a1real; isf = a1f32; kk = kg; }
            else           { p = A2; stride = a2stride; real = a2real; isf = a2f32; kk = kg - a1kw; }
            uint4 v = {0, 0, 0, 0};
            if (mg < M) {
                if (!isf) {
                    v = *(const uint4*)((const bf16*)p + (size_t)mg * stride + kk);
                } else {
                    const float* fp = (const float*)p + (size_t)mg * stride;
                    unsigned short us[8];
                    #pragma unroll
                    for (int j = 0; j < 8; j++)
                        us[j] = (kk + j < real) ? f2bf(fp[kk + j]) : (unsigned short)0;
                    v.x = us[0] | ((unsigned)us[1] << 16);
                    v.y = us[2] | ((unsigned)us[3] << 16);
                    v.z = us[4] | ((unsigned)us[5] << 16);
                    v.w = us[6] | ((unsigned)us[7] << 16);
                }
            }
            *(uint4*)&As[mloc * 40 + kq] = v;
        }
        {
            int kq = (tid & 3) * 8;
            #pragma unroll
            for (int it = 0; it < 2; ++it) {
                int nloc = (tid >> 2) + it * 128;
                *(uint4*)&Bs[nloc * 40 + kq] =
                    *(const uint4*)&WT1[(size_t)nloc * KT + k0 + kq];
            }
        }
        __syncthreads();
        short8 af[2], bw[4];
        #pragma unroll
        for (int mf = 0; mf < 2; mf++)
            af[mf] = *(const short8*)&As[(wr * 32 + mf * 16 + fr) * 40 + ko];
        #pragma unroll
        for (int nf = 0; nf < 4; nf++)
            bw[nf] = *(const short8*)&Bs[(wc * 64 + nf * 16 + fr) * 40 + ko];
        #pragma unroll
        for (int mf = 0; mf < 2; mf++)
            #pragma unroll
            for (int nf = 0; nf < 4; nf++)
                acc[mf][nf] = __builtin_amdgcn_mfma_f32_16x16x32_bf16(af[mf], bw[nf], acc[mf][nf], 0, 0, 0);
        __syncthreads();
    }

    #pragma unroll
    for (int mf = 0; mf < 2; mf++) {
        #pragma unroll
        for (int i = 0; i < 4; i++) {
            int mloc = wr * 32 + mf * 16 + (lane >> 4) * 4 + i;
            int gm = row0 + mloc;
            if (gm >= M) continue;
            #pragma unroll
            for (int nf = 0; nf < 4; nf++) {
                int gc = wc * 64 + nf * 16 + fr;
                out1[(size_t)gm * DD + gc] = hswish(acc[mf][nf][i] + bias1[gc]);
            }
        }
    }
}

// ---- final_pair64: BM=64 — [bond final -> out_bond] ∥ [node final -> out_node]
__global__ __launch_bounds__(512) void final_pair64(
    const bf16* __restrict__ IBbf, const bf16* __restrict__ MB,
    const bf16* __restrict__ WTbf, const float* __restrict__ b_bf,
    float* __restrict__ out_bond,
    const float* __restrict__ node, const bf16* __restrict__ MNf,
    const bf16* __restrict__ WTnf, const float* __restrict__ b_nf,
    float* __restrict__ out_node)
{
    __shared__ __align__(16) unsigned short As[64 * 40];    // 5.1 KB
    __shared__ __align__(16) unsigned short Bs[256 * 40];   // 20.5 KB
    int b = blockIdx.x;
    if (b < 3125) {
        bg64_body(IBbf, 160, 160, 160, 0, MB, 256, 256, 256, 0,
                  WTbf, 416, b_bf, out_bond, NE, b * 64, As, Bs);
    } else {
        bg64_body(node, FN, 160, FN, 1, MNf, 256, 256, 256, 0,
                  WTnf, 416, b_nf, out_node, NN, (b - 3125) * 64, As, Bs);
    }
}

extern "C" void kernel_launch(void* const* d_in, const int* in_sizes, int n_in,
                              void* d_out, int out_size, void* d_ws, size_t ws_size,
                              hipStream_t stream)
{
    const float* node  = (const float*)d_in[0];
    const float* bond  = (const float*)d_in[1];
    const int* connect = (const int*)d_in[2];
    const int* bnb     = (const int*)d_in[3];
    const float* w_node       = (const float*)d_in[4];
    const float* b_node       = (const float*)d_in[5];
    const float* w_node_final = (const float*)d_in[6];
    const float* b_node_final = (const float*)d_in[7];
    const float* w_bond       = (const float*)d_in[8];
    const float* b_bond       = (const float*)d_in[9];
    const float* w_bond_final = (const float*)d_in[10];
    const float* b_bond_final = (const float*)d_in[11];
    const float* w_z = (const float*)d_in[12];
    const float* b_z = (const float*)d_in[13];
    const float* w_r = (const float*)d_in[14];
    const float* b_r = (const float*)d_in[15];
    const float* u_  = (const float*)d_in[16];
    const float* w_m = (const float*)d_in[17];
    const float* b_m = (const float*)d_in[18];
    const float* w_n = (const float*)d_in[19];
    const float* b_n = (const float*)d_in[20];
    const float* u_n = (const float*)d_in[21];

    const int* i_idx = connect;
    const int* j_idx = connect + NE;
    const int* ij    = bnb;
    const int* ki    = bnb + NB;

    const size_t EBH = (size_t)NE * DD * 2;        // 102,400,000
    const size_t B_WT = (size_t)786432 * 2;        // 1.57 MB packed weights
    const size_t B_CSR = (size_t)NEPAD * 8 + (size_t)NB * 4
                       + (size_t)NNPAD * 8 + (size_t)NE * 4 + 2048;
    const size_t NEED = 5 * EBH + B_WT + B_CSR;    // ~519.4 MB (known to fit)

    float* out_node = (float*)d_out;
    float* out_bond = out_node + (size_t)NN * DD;

    if (ws_size < NEED) {
        fill_kernel<<<2048, 256, 0, stream>>>((float*)d_out, 1e6f, (long)out_size / 4);
        return;
    }

    char* base = (char*)d_ws;
    bf16* PR = (bf16*)base;                       base += EBH;   // also MN_final (l=2 out)
    bf16* MB = (bf16*)base;                       base += EBH;
    bf16* TR = (bf16*)base;                       base += EBH;   // also IBbf
    bf16* PZ = (bf16*)base;                       base += EBH;
    bf16* PM = (bf16*)base;                       base += EBH;
    char* wt = base;                              base += B_WT;
    int* offE  = (int*)base;                      base += (size_t)NEPAD * 4;
    int* curE  = (int*)base;                      base += (size_t)NEPAD * 4;
    int* nbLst = (int*)base;                      base += (size_t)NB * 4;
    int* offN  = (int*)base;                      base += (size_t)NNPAD * 4;
    int* curN  = (int*)base;                      base += (size_t)NNPAD * 4;
    int* agLst = (int*)base;                      base += (size_t)NE * 4;
    int* bsumE = (int*)base;                      base += 1024;
    int* bsumN = (int*)base;

    bf16* IBbf = TR;
    bf16* MNf = PR;                  // final MN (l=2 output); PR dead after l=2 seg_sr
    bf16* R = (bf16*)out_bond;
    bf16* S = R + (size_t)NE * DD;
    bf16* MN = (bf16*)out_node;
    bf16* PN = MN + (size_t)NN * DD;

    // packed-weight layout (elements) — must match pack_body
    bf16* wtb = (bf16*)wt;
    bf16* WTr  = wtb + 0;
    bf16* WTz1 = wtb + 40960;
    bf16* WTb  = wtb + 81920;
    bf16* WTm1 = wtb + 122880;
    bf16* WTn0 = wtb + 163840;
    bf16* WTn  = wtb + 204800;
    bf16* WTr2 = wtb + 245760;
    bf16* WTz2 = wtb + 311296;
    bf16* WTu  = wtb + 376832;
    bf16* WTnu = wtb + 442368;
    bf16* WTbf = wtb + 573440;
    bf16* WTnf = wtb + 679936;

    // ---- CSR build + weight pack + IB build (5 launches, overlapped) ----
    zero_pack<<<1176 + 3072, 256, 0, stream>>>(offE, offN,
        w_r, w_z, w_bond, w_m, w_node, w_n, u_, u_n,
        w_bond_final, w_node_final, wtb);
    count2_kernel<<<3125, 256, 0, stream>>>(ij, j_idx, offE, offN);
    scan_block2<<<294, 256, 0, stream>>>(offE, offN, bsumE, bsumN);
    scan_bsum2<<<2, 256, 0, stream>>>(bsumE, bsumN);
    scan_add_copy2<<<1176, 256, 0, stream>>>(offE, offN, bsumE, bsumN, curE, curN);
    lists_ib<<<3125 + 50000, 256, 0, stream>>>(ij, ki, j_idx, curE, curN,
                                               nbLst, agLst, node, bond, i_idx, IBbf);

    dim3 gBlend(3125, 2);

    // ---- pre-loop: quad GEMM BM=64 (3 blocks/CU) + MN/PN; then TR0 ----
    pre_quad64<<<9376, 512, 0, stream>>>(IBbf,
        WTr, WTz1, b_r, b_z, PR, PZ,
        WTb, WTm1, b_bond, b_m, MB, PM,
        node, WTn0, WTn, b_node, b_n, MN, PN);
    tr0_kernel<<<1563, 512, 0, stream>>>(MB, WTr2, TR);

    for (int l = 0; l < 3; l++) {
        seg_sr_kernel<<<(NE + 3) / 4, 256, 0, stream>>>(MB, TR, PR, offE, nbLst, S, R);
        blend2<<<gBlend, 512, 0, stream>>>(S, R, WTz2, WTu, PZ, PM, MB);
        // l<2: [TR_{l+1} || node-update in-place]
        // l=2: [node-update -> MNf (PR slot) || IB rebuild -> TR slot]
        int trb = (l < 2) ? 1563 : 0;
        int ibb = (l == 2) ? 25000 : 0;
        bf16* mnout = (l == 2) ? MNf : MN;
        pairk<<<trb + 782 + ibb, 512, 0, stream>>>(trb, MB, WTr2, TR,
                                                   MN, offN, agLst, WTnu, PN, mnout,
                                                   node, bond, i_idx, IBbf);
    }

    // ---- finals: direct f32 writes to d_out ----
    final_pair64<<<4688, 512, 0, stream>>>(IBbf, MB, WTbf, b_bond_final, out_bond,
                                           node, MNf, WTnf, b_node_final, out_node);
}

// Round 24
// 2188.123 us; speedup vs baseline: 1.0165x; 1.0165x over previous
//
#include <hip/hip_runtime.h>
#include <hip/hip_bf16.h>

#define NN 100000   // nodes
#define NE 200000   // bonds
#define NB 600000   // bond neighbours
#define FN 133
#define FB 14
#define FIB 147     // FN+FB
#define DD 256
#define NEPAD (196 * 1024)
#define NNPAD (98 * 1024)

typedef __hip_bfloat16 bf16;
typedef __attribute__((ext_vector_type(8))) short short8;   // 8 bf16 = 4 VGPR
typedef __attribute__((ext_vector_type(4))) float f32x4;

__device__ __forceinline__ float hswish(float x) {
    float c = fminf(fmaxf(x + 3.f, 0.f), 6.f);
    return x * c * (1.f / 6.f);
}
__device__ __forceinline__ float sigmoidf(float x) {
    return 1.f / (1.f + __expf(-x));
}
__device__ __forceinline__ float tanh_fast(float x) {
    return 1.f - 2.f / (1.f + __expf(2.f * x));
}
__device__ __forceinline__ float bf2f(unsigned short u) {
    union { unsigned int i; float f; } c; c.i = (unsigned int)u << 16; return c.f;
}
__device__ __forceinline__ unsigned short f2bf(float v) {
    bf16 b = __float2bfloat16(v);
    unsigned short u; __builtin_memcpy(&u, &b, 2); return u;
}
__device__ __forceinline__ void unp8(short8 v, float* f) {
    #pragma unroll
    for (int j = 0; j < 8; j++) {
        short s = v[j]; unsigned short u; __builtin_memcpy(&u, &s, 2);
        f[j] = bf2f(u);
    }
}
__device__ __forceinline__ uint4 pk8(const float* f) {
    uint4 v;
    v.x = f2bf(f[0]) | ((unsigned)f2bf(f[1]) << 16);
    v.y = f2bf(f[2]) | ((unsigned)f2bf(f[3]) << 16);
    v.z = f2bf(f[4]) | ((unsigned)f2bf(f[5]) << 16);
    v.w = f2bf(f[6]) | ((unsigned)f2bf(f[7]) << 16);
    return v;
}

// ---------------- fill (ws-guard sentinel only) -------------------------
__global__ __launch_bounds__(256) void fill_kernel(float* __restrict__ p, float v, long n4) {
    long i = (long)blockIdx.x * 256 + threadIdx.x;
    long st = (long)gridDim.x * 256;
    float4 z = {v, v, v, v};
    for (; i < n4; i += st) ((float4*)p)[i] = z;
}

// ---------------- IB row build (shared body) ----------------------------
__device__ __forceinline__ void ib_row(
    const float* __restrict__ node, const float* __restrict__ bond,
    const int* __restrict__ i_idx, bf16* __restrict__ IB, int row, int lane)
{
    if (lane >= 40) return;
    int src = i_idx[row];
    int c = lane * 4;
    unsigned short us[4];
    #pragma unroll
    for (int j = 0; j < 4; j++) {
        int k = c + j;
        float v = 0.f;
        if (k < FN)       v = node[(size_t)src * FN + k];
        else if (k < FIB) v = bond[(size_t)row * FB + (k - FN)];
        us[j] = f2bf(v);
    }
    ushort4 o = {us[0], us[1], us[2], us[3]};
    *(ushort4*)((unsigned short*)IB + (size_t)row * 160 + c) = o;
}

// ---------------- weight pack body (fixed layout, 786432 elems) ---------
__device__ __forceinline__ void pack_body(
    int idx,
    const float* __restrict__ w_r, const float* __restrict__ w_z,
    const float* __restrict__ w_bond, const float* __restrict__ w_m,
    const float* __restrict__ w_node, const float* __restrict__ w_n,
    const float* __restrict__ u_, const float* __restrict__ u_n,
    const float* __restrict__ w_bf, const float* __restrict__ w_nf,
    bf16* __restrict__ wt)
{
    if (idx >= 786432) return;
    float v = 0.f;
    if (idx < 245760) {
        int r = idx / 40960;
        int loc = idx - r * 40960;
        int n = loc / 160, k = loc % 160;
        const float* W = (r == 0) ? w_r : (r == 1) ? w_z : (r == 2) ? w_bond
                       : (r == 3) ? w_m : (r == 4) ? w_node : w_n;
        int K1 = (r < 4) ? FIB : FN;
        if (k < K1) v = W[(size_t)k * DD + n];
    } else if (idx < 442368) {
        int r = (idx - 245760) / 65536;
        int loc = (idx - 245760) - r * 65536;
        int n = loc / 256, k = loc % 256;
        const float* W = (r == 0) ? (w_r + (size_t)FIB * DD)
                       : (r == 1) ? (w_z + (size_t)FIB * DD) : u_;
        v = W[(size_t)k * DD + n];
    } else if (idx < 573440) {
        int loc = idx - 442368;
        int n = loc / 512, k = loc % 512;
        v = u_n[(size_t)k * DD + n];
    } else {
        int r = (idx - 573440) / 106496;
        int loc = (idx - 573440) - r * 106496;
        int n = loc / 416, k = loc % 416;
        const float* W = r ? w_nf : w_bf;
        int K1 = r ? FN : FIB;
        if (k < K1)        v = W[(size_t)k * DD + n];
        else if (k >= 160) v = W[(size_t)(K1 + k - 160) * DD + n];
    }
    wt[idx] = __float2bfloat16(v);
}

// ---- zero_pack: [zero CSR counts (1176 blk)] ∥ [pack weights (3072 blk)]
__global__ __launch_bounds__(256) void zero_pack(
    int* __restrict__ offE, int* __restrict__ offN,
    const float* __restrict__ w_r, const float* __restrict__ w_z,
    const float* __restrict__ w_bond, const float* __restrict__ w_m,
    const float* __restrict__ w_node, const float* __restrict__ w_n,
    const float* __restrict__ u_, const float* __restrict__ u_n,
    const float* __restrict__ w_bf, const float* __restrict__ w_nf,
    bf16* __restrict__ wt)
{
    int b = blockIdx.x;
    if (b < 1176) {
        int i = b * 256 + threadIdx.x;
        if (i < NEPAD) offE[i] = 0;
        else if (i < NEPAD + NNPAD) offN[i - NEPAD] = 0;
    } else {
        pack_body((b - 1176) * 256 + threadIdx.x,
                  w_r, w_z, w_bond, w_m, w_node, w_n, u_, u_n, w_bf, w_nf, wt);
    }
}

__global__ __launch_bounds__(256) void count2_kernel(
    const int* __restrict__ ij, const int* __restrict__ jidx,
    int* __restrict__ offE, int* __restrict__ offN)
{
    int i = blockIdx.x * 256 + threadIdx.x;
    if (i < NB) atomicAdd(&offE[ij[i]], 1);
    else if (i < NB + NE) atomicAdd(&offN[jidx[i - NB]], 1);
}

__global__ __launch_bounds__(256) void scan_block2(
    int* __restrict__ offE, int* __restrict__ offN,
    int* __restrict__ bsumE, int* __restrict__ bsumN)
{
    __shared__ int lds[256];
    int* data; int* bs; int bb;
    if ((int)blockIdx.x < 196) { data = offE; bs = bsumE; bb = blockIdx.x; }
    else                       { data = offN; bs = bsumN; bb = blockIdx.x - 196; }
    int base = bb * 1024 + threadIdx.x * 4;
    int c0 = data[base], c1 = data[base + 1], c2 = data[base + 2], c3 = data[base + 3];
    int t = c0 + c1 + c2 + c3;
    lds[threadIdx.x] = t;
    __syncthreads();
    int x = t;
    for (int off = 1; off < 256; off <<= 1) {
        int y = (threadIdx.x >= off) ? lds[threadIdx.x - off] : 0;
        __syncthreads();
        x += y; lds[threadIdx.x] = x;
        __syncthreads();
    }
    int excl = x - t;
    data[base] = excl; data[base + 1] = excl + c0;
    data[base + 2] = excl + c0 + c1; data[base + 3] = excl + c0 + c1 + c2;
    if (threadIdx.x == 255) bs[bb] = x;
}

__global__ __launch_bounds__(256) void scan_bsum2(int* __restrict__ bsumE, int* __restrict__ bsumN)
{
    __shared__ int lds[256];
    int* bs = blockIdx.x ? bsumN : bsumE;
    int n = blockIdx.x ? 98 : 196;
    int t = (threadIdx.x < n) ? bs[threadIdx.x] : 0;
    lds[threadIdx.x] = t;
    __syncthreads();
    int x = t;
    for (int off = 1; off < 256; off <<= 1) {
        int y = (threadIdx.x >= off) ? lds[threadIdx.x - off] : 0;
        __syncthreads();
        x += y; lds[threadIdx.x] = x;
        __syncthreads();
    }
    if (threadIdx.x < n) bs[threadIdx.x] = x - t;
}

// merged scan_add + copy (offX finalized and mirrored into curX)
__global__ __launch_bounds__(256) void scan_add_copy2(
    int* __restrict__ offE, int* __restrict__ offN,
    const int* __restrict__ bsumE, const int* __restrict__ bsumN,
    int* __restrict__ curE, int* __restrict__ curN)
{
    int i = blockIdx.x * 256 + threadIdx.x;
    if (i < NEPAD) {
        int v = offE[i] + bsumE[i >> 10];
        offE[i] = v; curE[i] = v;
    } else if (i < NEPAD + NNPAD) {
        int j = i - NEPAD;
        int v = offN[j] + bsumN[j >> 10];
        offN[j] = v; curN[j] = v;
    }
}

// ---- lists_ib: [CSR list fill (3125 blk)] ∥ [IB build (50000 blk)] -----
__global__ __launch_bounds__(256) void lists_ib(
    const int* __restrict__ ij, const int* __restrict__ ki, const int* __restrict__ jidx,
    int* __restrict__ curE, int* __restrict__ curN,
    int* __restrict__ nbLst, int* __restrict__ agLst,
    const float* __restrict__ node, const float* __restrict__ bond,
    const int* __restrict__ i_idx, bf16* __restrict__ IB)
{
    int b = blockIdx.x;
    if (b < 3125) {
        int i = b * 256 + threadIdx.x;
        if (i < NB) { int p = atomicAdd(&curE[ij[i]], 1); nbLst[p] = ki[i]; }
        else if (i < NB + NE) {
            int e = i - NB;
            int p = atomicAdd(&curN[jidx[e]], 1); agLst[p] = e;
        }
    } else {
        int row = (b - 3125) * 4 + (threadIdx.x >> 6);
        if (row < NE) ib_row(node, bond, i_idx, IB, row, threadIdx.x & 63);
    }
}

// -------- fused seg_s + seg_r: 2-way-unrolled CSR walk (ILP) ------------
__global__ __launch_bounds__(256) void seg_sr_kernel(
    const bf16* __restrict__ MB, const bf16* __restrict__ TR,
    const bf16* __restrict__ PR, const int* __restrict__ off,
    const int* __restrict__ lst,
    bf16* __restrict__ S, bf16* __restrict__ R)
{
    int sid = blockIdx.x * 4 + (threadIdx.x >> 6);
    if (sid >= NE) return;
    int lane = threadIdx.x & 63;
    ushort4 up = *(const ushort4*)((const unsigned short*)PR + (size_t)sid * DD + lane * 4);
    float p0 = bf2f(up.x), p1 = bf2f(up.y), p2 = bf2f(up.z), p3 = bf2f(up.w);
    int b = off[sid], e = off[sid + 1];
    float s0 = 0, s1 = 0, s2 = 0, s3 = 0;
    float r0 = 0, r1 = 0, r2 = 0, r3 = 0;
    int t = b;
    for (; t + 1 < e; t += 2) {
        int src0 = lst[t];
        int src1 = lst[t + 1];
        const unsigned short* m0p = (const unsigned short*)MB + (size_t)src0 * DD + lane * 4;
        const unsigned short* t0p = (const unsigned short*)TR + (size_t)src0 * DD + lane * 4;
        const unsigned short* m1p = (const unsigned short*)MB + (size_t)src1 * DD + lane * 4;
        const unsigned short* t1p = (const unsigned short*)TR + (size_t)src1 * DD + lane * 4;
        ushort4 um0 = *(const ushort4*)m0p;
        ushort4 ut0 = *(const ushort4*)t0p;
        ushort4 um1 = *(const ushort4*)m1p;
        ushort4 ut1 = *(const ushort4*)t1p;
        float a0 = bf2f(um0.x), a1 = bf2f(um0.y), a2 = bf2f(um0.z), a3 = bf2f(um0.w);
        float c0 = bf2f(um1.x), c1 = bf2f(um1.y), c2 = bf2f(um1.z), c3 = bf2f(um1.w);
        s0 += a0 + c0; s1 += a1 + c1; s2 += a2 + c2; s3 += a3 + c3;
        r0 += sigmoidf(p0 + bf2f(ut0.x)) * a0 + sigmoidf(p0 + bf2f(ut1.x)) * c0;
        r1 += sigmoidf(p1 + bf2f(ut0.y)) * a1 + sigmoidf(p1 + bf2f(ut1.y)) * c1;
        r2 += sigmoidf(p2 + bf2f(ut0.z)) * a2 + sigmoidf(p2 + bf2f(ut1.z)) * c2;
        r3 += sigmoidf(p3 + bf2f(ut0.w)) * a3 + sigmoidf(p3 + bf2f(ut1.w)) * c3;
    }
    if (t < e) {
        int src = lst[t];
        ushort4 um = *(const ushort4*)((const unsigned short*)MB + (size_t)src * DD + lane * 4);
        ushort4 ut = *(const ushort4*)((const unsigned short*)TR + (size_t)src * DD + lane * 4);
        float m0 = bf2f(um.x), m1 = bf2f(um.y), m2 = bf2f(um.z), m3 = bf2f(um.w);
        s0 += m0; s1 += m1; s2 += m2; s3 += m3;
        r0 += sigmoidf(p0 + bf2f(ut.x)) * m0;
        r1 += sigmoidf(p1 + bf2f(ut.y)) * m1;
        r2 += sigmoidf(p2 + bf2f(ut.z)) * m2;
        r3 += sigmoidf(p3 + bf2f(ut.w)) * m3;
    }
    ushort4 os = {f2bf(s0), f2bf(s1), f2bf(s2), f2bf(s3)};
    ushort4 orr = {f2bf(r0), f2bf(r1), f2bf(r2), f2bf(r3)};
    *(ushort4*)((unsigned short*)S + (size_t)sid * DD + lane * 4) = os;
    *(ushort4*)((unsigned short*)R + (size_t)sid * DD + lane * 4) = orr;
}

// ======== blend2: two sequential K=256 GEMM phases, k-step 64 ===========
__global__ __launch_bounds__(512) void blend2(
    const bf16* __restrict__ S, const bf16* __restrict__ R,
    const bf16* __restrict__ WTz2, const bf16* __restrict__ WTu,
    const bf16* __restrict__ PZ, const bf16* __restrict__ PM,
    bf16* __restrict__ MB)
{
    __shared__ __align__(16) unsigned short As[128 * 72];   // 18.4 KB
    __shared__ __align__(16) unsigned short Bs[128 * 72];   // 18.4 KB
    const int tid = threadIdx.x;
    const int row0 = blockIdx.x * 128, col0 = blockIdx.y * 128;
    const int lane = tid & 63, w = tid >> 6;
    const int wr = w >> 1, wc = w & 1;
    const int fr = lane & 15, ko = (lane >> 4) * 8;

    f32x4 acc1[2][4] = {};
    f32x4 acc2[2][4] = {};

    #pragma unroll
    for (int ph = 0; ph < 2; ph++) {
        const bf16* A = (ph == 0) ? S : R;
        const bf16* W = (ph == 0) ? WTz2 : WTu;
        for (int k0 = 0; k0 < DD; k0 += 64) {
            {
                int mloc = tid >> 2, kq = (tid & 3) * 16;
                int mg = row0 + mloc;
                uint4 va = {0, 0, 0, 0}, va2 = {0, 0, 0, 0};
                if (mg < NE) {
                    va  = *(const uint4*)((const unsigned short*)A + (size_t)mg * DD + k0 + kq);
                    va2 = *(const uint4*)((const unsigned short*)A + (size_t)mg * DD + k0 + kq + 8);
                }
                uint4 vb  = *(const uint4*)((const unsigned short*)W + (size_t)(col0 + mloc) * DD + k0 + kq);
                uint4 vb2 = *(const uint4*)((const unsigned short*)W + (size_t)(col0 + mloc) * DD + k0 + kq + 8);
                *(uint4*)&As[mloc * 72 + kq] = va;
                *(uint4*)&As[mloc * 72 + kq + 8] = va2;
                *(uint4*)&Bs[mloc * 72 + kq] = vb;
                *(uint4*)&Bs[mloc * 72 + kq + 8] = vb2;
            }
            __syncthreads();
            #pragma unroll
            for (int kk = 0; kk < 64; kk += 32) {
                short8 af[2], bf8[4];
                #pragma unroll
                for (int mf = 0; mf < 2; mf++)
                    af[mf] = *(const short8*)&As[(wr * 32 + mf * 16 + fr) * 72 + kk + ko];
                #pragma unroll
                for (int nf = 0; nf < 4; nf++)
                    bf8[nf] = *(const short8*)&Bs[(wc * 64 + nf * 16 + fr) * 72 + kk + ko];
                #pragma unroll
                for (int mf = 0; mf < 2; mf++)
                    #pragma unroll
                    for (int nf = 0; nf < 4; nf++) {
                        if (ph == 0)
                            acc1[mf][nf] = __builtin_amdgcn_mfma_f32_16x16x32_bf16(af[mf], bf8[nf], acc1[mf][nf], 0, 0, 0);
                        else
                            acc2[mf][nf] = __builtin_amdgcn_mfma_f32_16x16x32_bf16(af[mf], bf8[nf], acc2[mf][nf], 0, 0, 0);
                    }
            }
            __syncthreads();
        }
    }

    #pragma unroll
    for (int mf = 0; mf < 2; mf++) {
        #pragma unroll
        for (int i = 0; i < 4; i++) {
            int mloc = wr * 32 + mf * 16 + (lane >> 4) * 4 + i;
            int gm = row0 + mloc;
            if (gm >= NE) continue;
            #pragma unroll
            for (int nf = 0; nf < 4; nf++) {
                int gc = col0 + wc * 64 + nf * 16 + fr;
                size_t idx = (size_t)gm * DD + gc;
                float z  = sigmoidf(acc1[mf][nf][i] + __bfloat162float(PZ[idx]));
                float mm = tanh_fast(acc2[mf][nf][i] + __bfloat162float(PM[idx]));
                float s  = __bfloat162float(S[idx]);
                MB[idx] = __float2bfloat16((1.f - z) * s + z * mm);
            }
        }
    }
}

// ======== pairk: [TR-GEMM BN=256] ∥ [node-update w/ AGG] ∥ [IB build] ===
__global__ __launch_bounds__(512) void pairk(
    int trblocks,
    const bf16* __restrict__ MBn, const bf16* __restrict__ WTr2,
    bf16* __restrict__ TRo,
    const bf16* __restrict__ MN, const int* __restrict__ offN,
    const int* __restrict__ agLst, const bf16* __restrict__ WTnu,
    const bf16* __restrict__ PN, bf16* __restrict__ MNout,
    const float* __restrict__ node, const float* __restrict__ bond,
    const int* __restrict__ i_idx, bf16* __restrict__ IBout)
{
    __shared__ __align__(16) unsigned short As[128 * 40];   // 10 KB
    __shared__ __align__(16) unsigned short Bs[256 * 40];   // 20 KB
    const int tid = threadIdx.x, lane = tid & 63, w = tid >> 6;
    const int fr = lane & 15, ko = (lane >> 4) * 8;
    const int mloc = tid >> 2, kq = (tid & 3) * 8;

    if ((int)blockIdx.x < trblocks) {
        const int row0 = blockIdx.x * 128;
        const int wr = w >> 2, wc = w & 3;
        const int mg = row0 + mloc;
        f32x4 acc[4][4] = {};
        for (int k0 = 0; k0 < 256; k0 += 32) {
            uint4 v = {0, 0, 0, 0};
            if (mg < NE)
                v = *(const uint4*)((const unsigned short*)MBn + (size_t)mg * DD + k0 + kq);
            *(uint4*)&As[mloc * 40 + kq] = v;
            #pragma unroll
            for (int it = 0; it < 2; ++it) {
                int nloc = (tid >> 2) + it * 128;
                *(uint4*)&Bs[nloc * 40 + kq] =
                    *(const uint4*)((const unsigned short*)WTr2 + (size_t)nloc * DD + k0 + kq);
            }
            __syncthreads();
            short8 af[4], bw[4];
            #pragma unroll
            for (int mf = 0; mf < 4; mf++)
                af[mf] = *(const short8*)&As[(wr * 64 + mf * 16 + fr) * 40 + ko];
            #pragma unroll
            for (int nf = 0; nf < 4; nf++)
                bw[nf] = *(const short8*)&Bs[(wc * 64 + nf * 16 + fr) * 40 + ko];
            #pragma unroll
            for (int mf = 0; mf < 4; mf++)
                #pragma unroll
                for (int nf = 0; nf < 4; nf++)
                    acc[mf][nf] = __builtin_amdgcn_mfma_f32_16x16x32_bf16(af[mf], bw[nf], acc[mf][nf], 0, 0, 0);
            __syncthreads();
        }
        #pragma unroll
        for (int mf = 0; mf < 4; mf++)
            #pragma unroll
            for (int i = 0; i < 4; i++) {
                int ml = wr * 64 + mf * 16 + (lane >> 4) * 4 + i;
                int gm = row0 + ml;
                if (gm >= NE) continue;
                #pragma unroll
                for (int nf = 0; nf < 4; nf++) {
                    int gc = wc * 64 + nf * 16 + fr;
                    TRo[(size_t)gm * DD + gc] = __float2bfloat16(acc[mf][nf][i]);
                }
            }
    } else if ((int)blockIdx.x < trblocks + 782) {
        const int bx = blockIdx.x - trblocks;
        const int row0 = bx * 128;
        const int wr = w >> 2, wc = w & 3;
        const int mg = row0 + mloc;
        int eb = 0, ee = 0;
        if (mg < NN) { eb = offN[mg]; ee = offN[mg + 1]; }
        f32x4 acc[4][4] = {};
        for (int k0 = 0; k0 < 512; k0 += 32) {
            const int kg = k0 + kq;
            uint4 v = {0, 0, 0, 0};
            if (mg < NN) {
                if (kg < 256) {
                    v = *(const uint4*)((const unsigned short*)MN + (size_t)mg * DD + kg);
                } else {
                    const int kk = kg - 256;
                    float a[8] = {0, 0, 0, 0, 0, 0, 0, 0};
                    int t = eb;
                    for (; t + 1 < ee; t += 2) {
                        int s0i = agLst[t];
                        int s1i = agLst[t + 1];
                        short8 v0 = *(const short8*)((const unsigned short*)MBn + (size_t)s0i * DD + kk);
                        short8 v1 = *(const short8*)((const unsigned short*)MBn + (size_t)s1i * DD + kk);
                        float m0[8], m1[8];
                        unp8(v0, m0); unp8(v1, m1);
                        #pragma unroll
                        for (int j = 0; j < 8; j++) a[j] += m0[j] + m1[j];
                    }
                    if (t < ee) {
                        int src = agLst[t];
                        float m8[8];
                        unp8(*(const short8*)((const unsigned short*)MBn + (size_t)src * DD + kk), m8);
                        #pragma unroll
                        for (int j = 0; j < 8; j++) a[j] += m8[j];
                    }
                    v = pk8(a);
                }
            }
            *(uint4*)&As[mloc * 40 + kq] = v;
            #pragma unroll
            for (int it = 0; it < 2; ++it) {
                int nloc = (tid >> 2) + it * 128;
                *(uint4*)&Bs[nloc * 40 + kq] =
                    *(const uint4*)((const unsigned short*)WTnu + (size_t)nloc * 512 + k0 + kq);
            }
            __syncthreads();
            short8 af[4], bw[4];
            #pragma unroll
            for (int mf = 0; mf < 4; mf++)
                af[mf] = *(const short8*)&As[(wr * 64 + mf * 16 + fr) * 40 + ko];
            #pragma unroll
            for (int nf = 0; nf < 4; nf++)
                bw[nf] = *(const short8*)&Bs[(wc * 64 + nf * 16 + fr) * 40 + ko];
            #pragma unroll
            for (int mf = 0; mf < 4; mf++)
                #pragma unroll
                for (int nf = 0; nf < 4; nf++)
                    acc[mf][nf] = __builtin_amdgcn_mfma_f32_16x16x32_bf16(af[mf], bw[nf], acc[mf][nf], 0, 0, 0);
            __syncthreads();
        }
        #pragma unroll
        for (int mf = 0; mf < 4; mf++)
            #pragma unroll
            for (int i = 0; i < 4; i++) {
                int ml = wr * 64 + mf * 16 + (lane >> 4) * 4 + i;
                int gm = row0 + ml;
                if (gm >= NN) continue;
                #pragma unroll
                for (int nf = 0; nf < 4; nf++) {
                    int gc = wc * 64 + nf * 16 + fr;
                    size_t idx = (size_t)gm * DD + gc;
                    MNout[idx] = __float2bfloat16(
                        hswish(acc[mf][nf][i] + __bfloat162float(PN[idx])));
                }
            }
    } else {
        int b2 = blockIdx.x - trblocks - 782;
        int row = b2 * 8 + (tid >> 6);
        if (row < NE) ib_row(node, bond, i_idx, IBout, row, lane);
    }
}

// ======== pre_quad64: BM=64 — 4 GEMMs over one LDS-cached A (K=160) =====
// blocks 0..6249: bond quad (bx = b%3125, by = b/3125)
// blocks 6250..9375: node dual (bx = b2%1563, by = b2/1563)
__global__ __launch_bounds__(512) void pre_quad64(
    const bf16* __restrict__ IBbf,
    const bf16* __restrict__ WTr, const bf16* __restrict__ WTz1,
    const float* __restrict__ b_r, const float* __restrict__ b_z,
    bf16* __restrict__ PR, bf16* __restrict__ PZ,
    const bf16* __restrict__ WTb, const bf16* __restrict__ WTm1,
    const float* __restrict__ b_bond, const float* __restrict__ b_m,
    bf16* __restrict__ MB, bf16* __restrict__ PM,
    const float* __restrict__ node,
    const bf16* __restrict__ WTn0, const bf16* __restrict__ WTn,
    const float* __restrict__ b_node, const float* __restrict__ b_n,
    bf16* __restrict__ MN, bf16* __restrict__ PN)
{
    __shared__ __align__(16) unsigned short Af[64 * 168];   // 21 KB (stride-168 pad)
    __shared__ __align__(16) unsigned short B1[128 * 40];   // 10 KB
    __shared__ __align__(16) unsigned short B2[128 * 40];   // 10 KB
    const int tid = threadIdx.x;
    const int lane = tid & 63, w = tid >> 6;
    const int fr = lane & 15, ko = (lane >> 4) * 8;
    const int wr = w >> 1, wc = w & 1;      // 4x2 waves, MSPAN=16
    int b = blockIdx.x;

    if (b < 6250) {
        const int bx = b % 3125, by = b / 3125;
        const int row0 = bx * 64, col0 = by * 128;
        // ---- load full A tile (64 x 160 bf16) once ----
        #pragma unroll
        for (int it = 0; it < 3; ++it) {
            int idx = tid + it * 512;           // 0..1535 (need 1280)
            if (idx < 1280) {
                int mloc = idx / 20, kq = (idx % 20) * 8;
                int mg = row0 + mloc;
                uint4 v = *(const uint4*)((const unsigned short*)IBbf + (size_t)mg * 160 + kq);
                *(uint4*)&Af[mloc * 168 + kq] = v;
            }
        }
        __syncthreads();

        #pragma unroll
        for (int ph = 0; ph < 2; ph++) {
            const bf16* W1 = ph ? WTb : WTr;
            const bf16* W2 = ph ? WTm1 : WTz1;
            f32x4 a1[4] = {};
            f32x4 a2[4] = {};
            for (int k0 = 0; k0 < 160; k0 += 32) {
                {
                    int nloc = tid >> 2, kq = (tid & 3) * 8;
                    *(uint4*)&B1[nloc * 40 + kq] =
                        *(const uint4*)((const unsigned short*)W1 + (size_t)(col0 + nloc) * 160 + k0 + kq);
                    *(uint4*)&B2[nloc * 40 + kq] =
                        *(const uint4*)((const unsigned short*)W2 + (size_t)(col0 + nloc) * 160 + k0 + kq);
                }
                __syncthreads();
                short8 af = *(const short8*)&Af[(wr * 16 + fr) * 168 + k0 + ko];
                short8 b1f[4], b2f[4];
                #pragma unroll
                for (int nf = 0; nf < 4; nf++) {
                    b1f[nf] = *(const short8*)&B1[(wc * 64 + nf * 16 + fr) * 40 + ko];
                    b2f[nf] = *(const short8*)&B2[(wc * 64 + nf * 16 + fr) * 40 + ko];
                }
                #pragma unroll
                for (int nf = 0; nf < 4; nf++) {
                    a1[nf] = __builtin_amdgcn_mfma_f32_16x16x32_bf16(af, b1f[nf], a1[nf], 0, 0, 0);
                    a2[nf] = __builtin_amdgcn_mfma_f32_16x16x32_bf16(af, b2f[nf], a2[nf], 0, 0, 0);
                }
                __syncthreads();
            }
            // epilogue (no LDS use)
            #pragma unroll
            for (int i = 0; i < 4; i++) {
                int mloc = wr * 16 + (lane >> 4) * 4 + i;
                int gm = row0 + mloc;
                #pragma unroll
                for (int nf = 0; nf < 4; nf++) {
                    int gc = col0 + wc * 64 + nf * 16 + fr;
                    size_t idx = (size_t)gm * DD + gc;
                    if (ph == 0) {
                        PR[idx] = __float2bfloat16(a1[nf][i] + b_r[gc]);
                        PZ[idx] = __float2bfloat16(a2[nf][i] + b_z[gc]);
                    } else {
                        MB[idx] = __float2bfloat16(hswish(a1[nf][i] + b_bond[gc]));
                        PM[idx] = __float2bfloat16(a2[nf][i] + b_m[gc]);
                    }
                }
            }
        }
    } else {
        // ---- MN/PN dual: A = node (f32, K real 133, padded 160), BM=64 ----
        const int b2 = b - 6250;
        const int bx = b2 % 1563, by = b2 / 1563;
        const int row0 = bx * 64, col0 = by * 128;
        f32x4 a1[4] = {};
        f32x4 a2[4] = {};
        for (int k0 = 0; k0 < 160; k0 += 32) {
            if (tid < 256) {
                int mloc = tid >> 2, kq = (tid & 3) * 8;
                int mg = row0 + mloc;
                uint4 v = {0, 0, 0, 0};
                if (mg < NN) {
                    const float* fp = node + (size_t)mg * FN;
                    unsigned short us[8];
                    #pragma unroll
                    for (int j = 0; j < 8; j++) {
                        int kk = k0 + kq + j;
                        us[j] = (kk < FN) ? f2bf(fp[kk]) : (unsigned short)0;
                    }
                    v.x = us[0] | ((unsigned)us[1] << 16);
                    v.y = us[2] | ((unsigned)us[3] << 16);
                    v.z = us[4] | ((unsigned)us[5] << 16);
                    v.w = us[6] | ((unsigned)us[7] << 16);
                }
                *(uint4*)&Af[mloc * 40 + kq] = v;
            }
            {
                int nloc = tid >> 2, kq = (tid & 3) * 8;
                *(uint4*)&B1[nloc * 40 + kq] =
                    *(const uint4*)((const unsigned short*)WTn0 + (size_t)(col0 + nloc) * 160 + k0 + kq);
                *(uint4*)&B2[nloc * 40 + kq] =
                    *(const uint4*)((const unsigned short*)WTn + (size_t)(col0 + nloc) * 160 + k0 + kq);
            }
            __syncthreads();
            short8 af = *(const short8*)&Af[(wr * 16 + fr) * 40 + ko];
            short8 b1f[4], b2f[4];
            #pragma unroll
            for (int nf = 0; nf < 4; nf++) {
                b1f[nf] = *(const short8*)&B1[(wc * 64 + nf * 16 + fr) * 40 + ko];
                b2f[nf] = *(const short8*)&B2[(wc * 64 + nf * 16 + fr) * 40 + ko];
            }
            #pragma unroll
            for (int nf = 0; nf < 4; nf++) {
                a1[nf] = __builtin_amdgcn_mfma_f32_16x16x32_bf16(af, b1f[nf], a1[nf], 0, 0, 0);
                a2[nf] = __builtin_amdgcn_mfma_f32_16x16x32_bf16(af, b2f[nf], a2[nf], 0, 0, 0);
            }
            __syncthreads();
        }
        #pragma unroll
        for (int i = 0; i < 4; i++) {
            int mloc = wr * 16 + (lane >> 4) * 4 + i;
            int gm = row0 + mloc;
            if (gm >= NN) continue;
            #pragma unroll
            for (int nf = 0; nf < 4; nf++) {
                int gc = col0 + wc * 64 + nf * 16 + fr;
                size_t idx = (size_t)gm * DD + gc;
                MN[idx] = __float2bfloat16(hswish(a1[nf][i] + b_node[gc]));
                PN[idx] = __float2bfloat16(a2[nf][i] + b_n[gc]);
            }
        }
    }
}

// ---- tr0: TR_0 = MB @ WTr2 (BM=128, BN=256) ----------------------------
__global__ __launch_bounds__(512) void tr0_kernel(
    const bf16* __restrict__ MBn, const bf16* __restrict__ WTr2,
    bf16* __restrict__ TRo)
{
    __shared__ __align__(16) unsigned short As[128 * 40];
    __shared__ __align__(16) unsigned short Bs[256 * 40];
    const int tid = threadIdx.x, lane = tid & 63, w = tid >> 6;
    const int fr = lane & 15, ko = (lane >> 4) * 8;
    const int mloc = tid >> 2, kq = (tid & 3) * 8;
    const int row0 = blockIdx.x * 128;
    const int wr = w >> 2, wc = w & 3;
    const int mg = row0 + mloc;
    f32x4 acc[4][4] = {};
    for (int k0 = 0; k0 < 256; k0 += 32) {
        uint4 v = {0, 0, 0, 0};
        if (mg < NE)
            v = *(const uint4*)((const unsigned short*)MBn + (size_t)mg * DD + k0 + kq);
        *(uint4*)&As[mloc * 40 + kq] = v;
        #pragma unroll
        for (int it = 0; it < 2; ++it) {
            int nloc = (tid >> 2) + it * 128;
            *(uint4*)&Bs[nloc * 40 + kq] =
                *(const uint4*)((const unsigned short*)WTr2 + (size_t)nloc * DD + k0 + kq);
        }
        __syncthreads();
        short8 af[4], bw[4];
        #pragma unroll
        for (int mf = 0; mf < 4; mf++)
            af[mf] = *(const short8*)&As[(wr * 64 + mf * 16 + fr) * 40 + ko];
        #pragma unroll
        for (int nf = 0; nf < 4; nf++)
            bw[nf] = *(const short8*)&Bs[(wc * 64 + nf * 16 + fr) * 40 + ko];
        #pragma unroll
        for (int mf = 0; mf < 4; mf++)
            #pragma unroll
            for (int nf = 0; nf < 4; nf++)
                acc[mf][nf] = __builtin_amdgcn_mfma_f32_16x16x32_bf16(af[mf], bw[nf], acc[mf][nf], 0, 0, 0);
        __syncthreads();
    }
    #pragma unroll
    for (int mf = 0; mf < 4; mf++)
        #pragma unroll
        for (int i = 0; i < 4; i++) {
            int ml = wr * 64 + mf * 16 + (lane >> 4) * 4 + i;
            int gm = row0 + ml;
            if (gm >= NE) continue;
            #pragma unroll
            for (int nf = 0; nf < 4; nf++) {
                int gc = wc * 64 + nf * 16 + fr;
                TRo[(size_t)gm * DD + gc] = __float2bfloat16(acc[mf][nf][i]);
            }
        }
}

// ---------------- bg64_body: BM=64, BN=256, NT=512 (f32 out) ------------
__device__ __forceinline__ void bg64_body(
    const void* __restrict__ A1, int a1stride, int a1kw, int a1real, int a1f32,
    const void* __restrict__ A2, int a2stride, int a2kw, int a2real, int a2f32,
    const bf16* __restrict__ WT1, int KT, const float* __restrict__ bias1,
    float* __restrict__ out1, int M, int row0,
    unsigned short* As, unsigned short* Bs)
{
    const int tid = threadIdx.x;
    const int lane = tid & 63, w = tid >> 6;
    const int wr = w >> 2, wc = w & 3;
    const int fr = lane & 15, ko = (lane >> 4) * 8;

    f32x4 acc[2][4] = {};

    for (int k0 = 0; k0 < KT; k0 += 32) {
        if (tid < 256) {
            int mloc = tid >> 2, kq = (tid & 3) * 8;
            int mg = row0 + mloc;
            int kg = k0 + kq;
            const void* p; int stride, real, isf; int kk;
            if (kg < a1kw) { p = A1; stride = a1stride; real = a1real; isf = a1f32; kk = kg; }
            else           { p = A2; stride = a2stride; real = a2real; isf = a2f32; kk = kg - a1kw; }
            uint4 v = {0, 0, 0, 0};
            if (mg < M) {
                if (!isf) {
                    v = *(const uint4*)((const bf16*)p + (size_t)mg * stride + kk);
                } else {
                    const float* fp = (const float*)p + (size_t)mg * stride;
                    unsigned short us[8];
                    #pragma unroll
                    for (int j = 0; j < 8; j++)
                        us[j] = (kk + j < real) ? f2bf(fp[kk + j]) : (unsigned short)0;
                    v.x = us[0] | ((unsigned)us[1] << 16);
                    v.y = us[2] | ((unsigned)us[3] << 16);
                    v.z = us[4] | ((unsigned)us[5] << 16);
                    v.w = us[6] | ((unsigned)us[7] << 16);
                }
            }
            *(uint4*)&As[mloc * 40 + kq] = v;
        }
        {
            int kq = (tid & 3) * 8;
            #pragma unroll
            for (int it = 0; it < 2; ++it) {
                int nloc = (tid >> 2) + it * 128;
                *(uint4*)&Bs[nloc * 40 + kq] =
                    *(const uint4*)&WT1[(size_t)nloc * KT + k0 + kq];
            }
        }
        __syncthreads();
        short8 af[2], bw[4];
        #pragma unroll
        for (int mf = 0; mf < 2; mf++)
            af[mf] = *(const short8*)&As[(wr * 32 + mf * 16 + fr) * 40 + ko];
        #pragma unroll
        for (int nf = 0; nf < 4; nf++)
            bw[nf] = *(const short8*)&Bs[(wc * 64 + nf * 16 + fr) * 40 + ko];
        #pragma unroll
        for (int mf = 0; mf < 2; mf++)
            #pragma unroll
            for (int nf = 0; nf < 4; nf++)
                acc[mf][nf] = __builtin_amdgcn_mfma_f32_16x16x32_bf16(af[mf], bw[nf], acc[mf][nf], 0, 0, 0);
        __syncthreads();
    }

    #pragma unroll
    for (int mf = 0; mf < 2; mf++) {
        #pragma unroll
        for (int i = 0; i < 4; i++) {
            int mloc = wr * 32 + mf * 16 + (lane >> 4) * 4 + i;
            int gm = row0 + mloc;
            if (gm >= M) continue;
            #pragma unroll
            for (int nf = 0; nf < 4; nf++) {
                int gc = wc * 64 + nf * 16 + fr;
                out1[(size_t)gm * DD + gc] = hswish(acc[mf][nf][i] + bias1[gc]);
            }
        }
    }
}

// ---- final_pair64: BM=64 — [bond final -> out_bond] ∥ [node final -> out_node]
__global__ __launch_bounds__(512) void final_pair64(
    const bf16* __restrict__ IBbf, const bf16* __restrict__ MB,
    const bf16* __restrict__ WTbf, const float* __restrict__ b_bf,
    float* __restrict__ out_bond,
    const float* __restrict__ node, const bf16* __restrict__ MNf,
    const bf16* __restrict__ WTnf, const float* __restrict__ b_nf,
    float* __restrict__ out_node)
{
    __shared__ __align__(16) unsigned short As[64 * 40];    // 5.1 KB
    __shared__ __align__(16) unsigned short Bs[256 * 40];   // 20.5 KB
    int b = blockIdx.x;
    if (b < 3125) {
        bg64_body(IBbf, 160, 160, 160, 0, MB, 256, 256, 256, 0,
                  WTbf, 416, b_bf, out_bond, NE, b * 64, As, Bs);
    } else {
        bg64_body(node, FN, 160, FN, 1, MNf, 256, 256, 256, 0,
                  WTnf, 416, b_nf, out_node, NN, (b - 3125) * 64, As, Bs);
    }
}

extern "C" void kernel_launch(void* const* d_in, const int* in_sizes, int n_in,
                              void* d_out, int out_size, void* d_ws, size_t ws_size,
                              hipStream_t stream)
{
    const float* node  = (const float*)d_in[0];
    const float* bond  = (const float*)d_in[1];
    const int* connect = (const int*)d_in[2];
    const int* bnb     = (const int*)d_in[3];
    const float* w_node       = (const float*)d_in[4];
    const float* b_node       = (const float*)d_in[5];
    const float* w_node_final = (const float*)d_in[6];
    const float* b_node_final = (const float*)d_in[7];
    const float* w_bond       = (const float*)d_in[8];
    const float* b_bond       = (const float*)d_in[9];
    const float* w_bond_final = (const float*)d_in[10];
    const float* b_bond_final = (const float*)d_in[11];
    const float* w_z = (const float*)d_in[12];
    const float* b_z = (const float*)d_in[13];
    const float* w_r = (const float*)d_in[14];
    const float* b_r = (const float*)d_in[15];
    const float* u_  = (const float*)d_in[16];
    const float* w_m = (const float*)d_in[17];
    const float* b_m = (const float*)d_in[18];
    const float* w_n = (const float*)d_in[19];
    const float* b_n = (const float*)d_in[20];
    const float* u_n = (const float*)d_in[21];

    const int* i_idx = connect;
    const int* j_idx = connect + NE;
    const int* ij    = bnb;
    const int* ki    = bnb + NB;

    const size_t EBH = (size_t)NE * DD * 2;        // 102,400,000
    const size_t B_WT = (size_t)786432 * 2;        // 1.57 MB packed weights
    const size_t B_CSR = (size_t)NEPAD * 8 + (size_t)NB * 4
                       + (size_t)NNPAD * 8 + (size_t)NE * 4 + 2048;
    const size_t NEED = 5 * EBH + B_WT + B_CSR;    // ~519.4 MB (known to fit)

    float* out_node = (float*)d_out;
    float* out_bond = out_node + (size_t)NN * DD;

    if (ws_size < NEED) {
        fill_kernel<<<2048, 256, 0, stream>>>((float*)d_out, 1e6f, (long)out_size / 4);
        return;
    }

    char* base = (char*)d_ws;
    bf16* PR = (bf16*)base;                       base += EBH;   // also MN_final (l=2 out)
    bf16* MB = (bf16*)base;                       base += EBH;
    bf16* TR = (bf16*)base;                       base += EBH;   // also IBbf
    bf16* PZ = (bf16*)base;                       base += EBH;
    bf16* PM = (bf16*)base;                       base += EBH;
    char* wt = base;                              base += B_WT;
    int* offE  = (int*)base;                      base += (size_t)NEPAD * 4;
    int* curE  = (int*)base;                      base += (size_t)NEPAD * 4;
    int* nbLst = (int*)base;                      base += (size_t)NB * 4;
    int* offN  = (int*)base;                      base += (size_t)NNPAD * 4;
    int* curN  = (int*)base;                      base += (size_t)NNPAD * 4;
    int* agLst = (int*)base;                      base += (size_t)NE * 4;
    int* bsumE = (int*)base;                      base += 1024;
    int* bsumN = (int*)base;

    bf16* IBbf = TR;
    bf16* MNf = PR;                  // final MN (l=2 output); PR dead after l=2 seg_sr
    bf16* R = (bf16*)out_bond;
    bf16* S = R + (size_t)NE * DD;
    bf16* MN = (bf16*)out_node;
    bf16* PN = MN + (size_t)NN * DD;

    // packed-weight layout (elements) — must match pack_body
    bf16* wtb = (bf16*)wt;
    bf16* WTr  = wtb + 0;
    bf16* WTz1 = wtb + 40960;
    bf16* WTb  = wtb + 81920;
    bf16* WTm1 = wtb + 122880;
    bf16* WTn0 = wtb + 163840;
    bf16* WTn  = wtb + 204800;
    bf16* WTr2 = wtb + 245760;
    bf16* WTz2 = wtb + 311296;
    bf16* WTu  = wtb + 376832;
    bf16* WTnu = wtb + 442368;
    bf16* WTbf = wtb + 573440;
    bf16* WTnf = wtb + 679936;

    // ---- CSR build + weight pack + IB build (5 launches, overlapped) ----
    zero_pack<<<1176 + 3072, 256, 0, stream>>>(offE, offN,
        w_r, w_z, w_bond, w_m, w_node, w_n, u_, u_n,
        w_bond_final, w_node_final, wtb);
    count2_kernel<<<3125, 256, 0, stream>>>(ij, j_idx, offE, offN);
    scan_block2<<<294, 256, 0, stream>>>(offE, offN, bsumE, bsumN);
    scan_bsum2<<<2, 256, 0, stream>>>(bsumE, bsumN);
    scan_add_copy2<<<1176, 256, 0, stream>>>(offE, offN, bsumE, bsumN, curE, curN);
    lists_ib<<<3125 + 50000, 256, 0, stream>>>(ij, ki, j_idx, curE, curN,
                                               nbLst, agLst, node, bond, i_idx, IBbf);

    dim3 gB2(1563, 2);

    // ---- pre-loop: quad GEMM BM=64 (3 blocks/CU) + MN/PN; then TR0 ----
    pre_quad64<<<9376, 512, 0, stream>>>(IBbf,
        WTr, WTz1, b_r, b_z, PR, PZ,
        WTb, WTm1, b_bond, b_m, MB, PM,
        node, WTn0, WTn, b_node, b_n, MN, PN);
    tr0_kernel<<<1563, 512, 0, stream>>>(MB, WTr2, TR);

    for (int l = 0; l < 3; l++) {
        seg_sr_kernel<<<(NE + 3) / 4, 256, 0, stream>>>(MB, TR, PR, offE, nbLst, S, R);
        blend2<<<gB2, 512, 0, stream>>>(S, R, WTz2, WTu, PZ, PM, MB);
        // l<2: [TR_{l+1} || node-update in-place]
        // l=2: [node-update -> MNf (PR slot) || IB rebuild -> TR slot]
        int trb = (l < 2) ? 1563 : 0;
        int ibb = (l == 2) ? 25000 : 0;
        bf16* mnout = (l == 2) ? MNf : MN;
        pairk<<<trb + 782 + ibb, 512, 0, stream>>>(trb, MB, WTr2, TR,
                                                   MN, offN, agLst, WTnu, PN, mnout,
                                                   node, bond, i_idx, IBbf);
    }

    // ---- finals: direct f32 writes to d_out ----
    final_pair64<<<4688, 512, 0, stream>>>(IBbf, MB, WTbf, b_bond_final, out_bond,
                                           node, MNf, WTnf, b_node_final, out_node);
}